// Round 7
// baseline (148.995 us; speedup 1.0000x reference)
//
#include <hip/hip_runtime.h>
#include <cstdint>

#define CN (384*1024)          // 393216
#define BCN (16*CN)            // 6291456
#define EPS 1e-5f
#define LCAP 24                // index-list capacity per (t,b,n) column

// workspace layout (bytes)
#define WPT_OFF   0u           // f32[384][384] = 589824
#define WQB_OFF   589824u      // bf16-as-u16[385][384] = 295680 (row 384 = zeros), ends 885504
#define QINV_OFF  1179648u
#define QOFF_OFF  (QINV_OFF + 1536u)
#define PINV_OFF  (QINV_OFF + 3072u)
#define POFF_OFF  (QINV_OFF + 4608u)
#define C0_OFF    (QINV_OFF + 6144u)
#define LCNT_OFF  1187840u     // u8[65536], ends 1253376
#define LISTS_OFF 2097152u     // u16[65536][24] premultiplied offsets (idx*3), 3MB, ends 5242880
#define XMT_OFF   5242880u     // u64[4][16][1024][6] c-packed spikes, ends 8388608
#define XM_OFF    8388608u     // u64[4][16][16][384] n-packed spikes, ends 11534336
#define MST_OFF   XM_OFF       // masked q-spikes (new word layout, see k2); reuses xm

// ---------------- K0a: transposes: wp -> f32 wpT, wq -> bf16 wqb (+ zero row) ------
__global__ __launch_bounds__(256) void k0_transpose(const float* __restrict__ wq,
                                                    const float* __restrict__ wp,
                                                    char* __restrict__ ws) {
    int bid = blockIdx.x;
    if (bid < 576) {
        int i = bid * 256 + threadIdx.x;             // 0..147455
        int c = i / 384, o = i % 384;
        ((float*)(ws + WPT_OFF))[c * 384 + o] = wp[o * 384 + c];
    } else {
        int j = (bid - 576) * 256 + threadIdx.x;     // 0..147967
        if (j >= 147840) return;                     // 385*384
        int r = j / 384, o = j % 384;
        unsigned short v = 0;
        if (r < 384) {
            unsigned u = __float_as_uint(wq[o * 384 + r]);
            v = (unsigned short)((u + 0x7fffu + ((u >> 16) & 1u)) >> 16);  // rne bf16
        }
        ((unsigned short*)(ws + WQB_OFF))[j] = v;
    }
}

// ---------------- K0b: BN constants ----------------
__global__ void k0_consts(const float* __restrict__ qg, const float* __restrict__ qb,
                          const float* __restrict__ qm, const float* __restrict__ qv,
                          const float* __restrict__ pg, const float* __restrict__ pb,
                          const float* __restrict__ pm, const float* __restrict__ pv,
                          const float* __restrict__ bp, char* __restrict__ ws) {
    int i = threadIdx.x;                         // 384 threads
    float qi = qg[i] / sqrtf(qv[i] + EPS);
    ((float*)(ws + QINV_OFF))[i] = qi;
    ((float*)(ws + QOFF_OFF))[i] = qb[i] - qm[i] * qi;
    float pi = pg[i] / sqrtf(pv[i] + EPS);
    float po = pb[i] - pm[i] * pi;
    ((float*)(ws + PINV_OFF))[i] = pi;
    ((float*)(ws + POFF_OFF))[i] = po;
    ((float*)(ws + C0_OFF))[i] = bp[i] * pi + po;   // output value when GEMM2 input is all-zero
}

// ---------------- K1: shortcut LIF -> n-packed spike bitmasks ----------------
__global__ __launch_bounds__(256) void k1_lif(const float* __restrict__ x,
                                              unsigned long long* __restrict__ xm) {
    int wid  = (blockIdx.x * 256 + threadIdx.x) >> 6;   // 0..98303
    int lane = threadIdx.x & 63;
    int c = wid % 384;
    int g = (wid / 384) & 15;
    int b = wid / (384 * 16);
    const float* xp = x + (size_t)b * CN + (size_t)c * 1024 + g * 64 + lane;
    float v = 0.f;
    #pragma unroll
    for (int t = 0; t < 4; ++t) {
        float xv = xp[(size_t)t * BCN];
        float h = v + (xv - v) * 0.5f;                  // v + (x - v)/tau, tau = 2
        bool s = (h >= 1.0f);
        unsigned long long m = __ballot(s);
        v = s ? 0.f : h;
        if (lane == 0) xm[(((size_t)t * 16 + b) * 16 + g) * 384 + c] = m;
    }
}

// ---------------- K1b: 64x64 bit transpose: n-packed -> c-packed ----------------
__global__ __launch_bounds__(256) void k1b_transpose(const unsigned long long* __restrict__ xm,
                                                     unsigned long long* __restrict__ xmT) {
    int wid  = (blockIdx.x * 256 + threadIdx.x) >> 6;   // 0..6143
    int lane = threadIdx.x & 63;
    int cg = wid % 6;
    int g  = (wid / 6) % 16;
    int tb = wid / 96;                                  // t*16 + b
    unsigned long long W = xm[((size_t)tb * 16 + g) * 384 + cg * 64 + lane];
    unsigned long long T = 0ull;
    #pragma unroll
    for (int k = 0; k < 64; ++k) {
        unsigned long long bk = __ballot((W >> k) & 1ull);  // bit c = spike(c, n=g*64+k)
        if (lane == k) T = bk;
    }
    xmT[((size_t)tb * 1024 + g * 64 + lane) * 6 + cg] = T;
}

// ---------------- K1c: c-packed bitmasks -> padded u16 offset lists ----------------
// Entry = row_index*3 (byte offset / 256). Pad last 8-batch with 1152 (= zero row 384).
// k>LCAP: lcnt=0xFF -> k2 bitmask fallback (any-input correct).
__global__ __launch_bounds__(256) void k1c_lists(const unsigned long long* __restrict__ xmT,
                                                 unsigned short* __restrict__ lists,
                                                 unsigned char* __restrict__ lcnt) {
    int col = blockIdx.x * 256 + threadIdx.x;           // 0..65535
    const unsigned long long* mp = xmT + (size_t)col * 6;
    unsigned short* lp = lists + (size_t)col * LCAP;
    int k = 0;
    #pragma unroll
    for (int cg = 0; cg < 6; ++cg) {
        unsigned long long m = mp[cg];
        while (m) {
            int j = __builtin_ctzll(m);
            m &= m - 1;
            if (k < LCAP) lp[k] = (unsigned short)((cg * 64 + j) * 3);
            ++k;
        }
    }
    if (k > LCAP) { lcnt[col] = 0xFF; return; }
    int r = (k + 7) >> 3;
    for (int i = k; i < r * 8; ++i) lp[i] = 1152;       // 384*3 -> zero row
    lcnt[col] = (unsigned char)r;
}

// ---------------- K2: saddr gather GEMM1 + BN + q-LIF + attn mask ----------------
// block = (b, 16-n tile); 384 threads = 2 n-streams x 192 threads; thread owns
// o-pair (2*pj, 2*pj+1) read as one u32 (two bf16). Row pointers are wave-uniform
// (readfirstlane -> SGPR pointer) so weight loads are saddr-form: 0 addr VALU.
#define GATHER8(IW, WV) do {                                                   \
    unsigned W0_ = __builtin_amdgcn_readfirstlane((IW).x);                     \
    unsigned W1_ = __builtin_amdgcn_readfirstlane((IW).y);                     \
    unsigned W2_ = __builtin_amdgcn_readfirstlane((IW).z);                     \
    unsigned W3_ = __builtin_amdgcn_readfirstlane((IW).w);                     \
    const char* r0_ = wqc + ((W0_ & 0xFFFFu) << 8);                            \
    const char* r1_ = wqc + ((W0_ >> 16) << 8);                                \
    const char* r2_ = wqc + ((W1_ & 0xFFFFu) << 8);                            \
    const char* r3_ = wqc + ((W1_ >> 16) << 8);                                \
    const char* r4_ = wqc + ((W2_ & 0xFFFFu) << 8);                            \
    const char* r5_ = wqc + ((W2_ >> 16) << 8);                                \
    const char* r6_ = wqc + ((W3_ & 0xFFFFu) << 8);                            \
    const char* r7_ = wqc + ((W3_ >> 16) << 8);                                \
    WV[0] = *(const unsigned*)(r0_ + voff); WV[1] = *(const unsigned*)(r1_ + voff); \
    WV[2] = *(const unsigned*)(r2_ + voff); WV[3] = *(const unsigned*)(r3_ + voff); \
    WV[4] = *(const unsigned*)(r4_ + voff); WV[5] = *(const unsigned*)(r5_ + voff); \
    WV[6] = *(const unsigned*)(r6_ + voff); WV[7] = *(const unsigned*)(r7_ + voff); \
} while (0)

#define BLO(w) __uint_as_float((w) << 16)
#define BHI(w) __uint_as_float((w) & 0xFFFF0000u)
#define ACC8(WV, AL, AH) do {                                                  \
    AL += ((BLO(WV[0]) + BLO(WV[1])) + (BLO(WV[2]) + BLO(WV[3])))              \
        + ((BLO(WV[4]) + BLO(WV[5])) + (BLO(WV[6]) + BLO(WV[7])));             \
    AH += ((BHI(WV[0]) + BHI(WV[1])) + (BHI(WV[2]) + BHI(WV[3])))              \
        + ((BHI(WV[4]) + BHI(WV[5])) + (BHI(WV[6]) + BHI(WV[7])));             \
} while (0)

__global__ __launch_bounds__(384) void k2_qpath(const char* __restrict__ wqc,
                                                const float* __restrict__ qinv_,
                                                const float* __restrict__ qoff_,
                                                const unsigned short* __restrict__ lists,
                                                const unsigned char* __restrict__ lcnt,
                                                const unsigned long long* __restrict__ xmT,
                                                const unsigned char* __restrict__ ak,
                                                const unsigned char* __restrict__ av,
                                                unsigned long long* __restrict__ msT) {
    const int tid  = threadIdx.x;
    const int s    = tid / 192;                  // n-stream (waves 0-2 / 3-5)
    const int pj   = tid - s * 192;              // o-pair index 0..191
    const int lane = tid & 63;
    const int wv_  = (tid >> 6) % 3;             // wave within stream -> o-base 128*wv_
    const int nt   = blockIdx.x & 63;
    const int b    = blockIdx.x >> 6;
    const int voff = pj * 4;                     // divergent byte offset within row
    const float2 qi2 = ((const float2*)qinv_)[pj];
    const float2 qo2 = ((const float2*)qoff_)[pj];

    for (int nl = 0; nl < 8; ++nl) {
        const int n = nt * 16 + s * 8 + nl;
        int col[4]; unsigned rn[4];
        uint4 iw0[4], iw1[4];
        #pragma unroll
        for (int t = 0; t < 4; ++t) {
            col[t] = ((t * 16 + b) << 10) + n;
            const uint4* lp = (const uint4*)(lists + (size_t)col[t] * LCAP);
            iw0[t] = lp[0]; iw1[t] = lp[1];
        }
        #pragma unroll
        for (int t = 0; t < 4; ++t)
            rn[t] = __builtin_amdgcn_readfirstlane((unsigned)lcnt[col[t]]);
        float aL[4], aH[4];
        #pragma unroll
        for (int t = 0; t < 4; ++t) { aL[t] = 0.f; aH[t] = 0.f; }

        unsigned w0_[4][8];
        #pragma unroll
        for (int t = 0; t < 4; ++t)
            if (rn[t] >= 1 && rn[t] != 0xFFu) GATHER8(iw0[t], w0_[t]);
        #pragma unroll
        for (int t = 0; t < 4; ++t)
            if (rn[t] >= 1 && rn[t] != 0xFFu) ACC8(w0_[t], aL[t], aH[t]);
        #pragma unroll
        for (int t = 0; t < 4; ++t)
            if (rn[t] >= 2 && rn[t] != 0xFFu) GATHER8(iw1[t], w0_[t]);
        #pragma unroll
        for (int t = 0; t < 4; ++t)
            if (rn[t] >= 2 && rn[t] != 0xFFu) ACC8(w0_[t], aL[t], aH[t]);
        #pragma unroll
        for (int t = 0; t < 4; ++t)
            if (rn[t] == 3) {                     // rare third round
                uint4 iw2 = ((const uint4*)(lists + (size_t)col[t] * LCAP))[2];
                unsigned wv2[8];
                GATHER8(iw2, wv2);
                ACC8(wv2, aL[t], aH[t]);
            }
        #pragma unroll
        for (int t = 0; t < 4; ++t)
            if (rn[t] == 0xFFu) {                 // overflow fallback (any-input correct)
                const unsigned long long* mp = xmT + (size_t)col[t] * 6;
                #pragma unroll
                for (int cg = 0; cg < 6; ++cg) {
                    unsigned long long mm = mp[cg];
                    while (mm) {
                        int j = __builtin_ctzll(mm);
                        mm &= mm - 1;
                        unsigned ww = *(const unsigned*)(wqc + (cg * 64 + j) * 768 + voff);
                        aL[t] += BLO(ww); aH[t] += BHI(ww);
                    }
                }
            }

        // BN + LIF + attn-mask epilogue for the two owned o's
        float vL = 0.f, vH = 0.f;
        #pragma unroll
        for (int t = 0; t < 4; ++t) {
            float qL = aL[t] * qi2.x + qo2.x;
            float qH = aH[t] * qi2.y + qo2.y;
            float hL = 0.5f * (vL + qL);
            float hH = 0.5f * (vH + qH);
            bool sL = (hL >= 1.0f), sH = (hH >= 1.0f);
            vL = sL ? 0.f : hL;  vH = sH ? 0.f : hH;
            if (sL) {   // rare: attn-mask lookup only on q-spike
                size_t ix = ((size_t)((t * 16 + b) * 384 + 2 * pj) << 10) + n;
                sL = (ak[ix] != 0) && (av[ix] != 0);
            }
            if (sH) {
                size_t ix = ((size_t)((t * 16 + b) * 384 + 2 * pj + 1) << 10) + n;
                sH = (ak[ix] != 0) && (av[ix] != 0);
            }
            unsigned long long bL = __ballot(sL);
            unsigned long long bH = __ballot(sH);
            // word u=2*wv_+h: bit l -> o = 128*wv_ + 2*l + h
            if (lane == 0) {
                msT[(size_t)col[t] * 6 + 2 * wv_]     = bL;
                msT[(size_t)col[t] * 6 + 2 * wv_ + 1] = bH;
            }
        }
    }
}

// ---------------- K3: proj GEMM2 + bias + BN (gather-based, atomic-free) ----------
__global__ __launch_bounds__(384) void k3_proj(const float* __restrict__ wpT,
                                               const float* __restrict__ pinv_,
                                               const float* __restrict__ poff_,
                                               const float* __restrict__ bp,
                                               const float* __restrict__ c0,
                                               const unsigned long long* __restrict__ msT,
                                               float* __restrict__ out) {
    __shared__ unsigned int wflag[6];
    const int tid = threadIdx.x;
    const int bid = blockIdx.x;
    const int g = bid & 15, b = (bid >> 4) & 15, t = bid >> 8;
    const unsigned long long* mbase = msT + ((size_t)(t * 16 + b) * 1024 + g * 64) * 6;
    unsigned long long m = mbase[tid];           // 384 words: n-local = tid/6, u = tid%6
    unsigned long long anyb = __ballot(m != 0ull);
    if ((tid & 63) == 0) wflag[tid >> 6] = (anyb != 0ull) ? 1u : 0u;
    __syncthreads();
    unsigned int any = wflag[0] | wflag[1] | wflag[2] | wflag[3] | wflag[4] | wflag[5];
    size_t obase = (size_t)(t * 16 + b) * 384;

    if (!any) {
        // all-zero GEMM2 input: out = bp*inv + off, coalesced float4 stores
        #pragma unroll
        for (int k = 0; k < 16; ++k) {
            int i = tid + k * 384;               // 6144 float4 units in the (384o x 64n) tile
            int o = i >> 4, n4 = i & 15;
            float vv = c0[o];
            float4* dst = (float4*)out + (obase + o) * 256 + g * 16 + n4;
            *dst = make_float4(vv, vv, vv, vv);
        }
        return;
    }
    // slow path (never taken on this input): per-n VGPR gather.
    // word u: bit l -> input channel 128*(u>>1) + 2*l + (u&1)   [matches k2's layout]
    float pi = pinv_[tid], po = poff_[tid], bb = bp[tid];
    for (int nl = 0; nl < 64; ++nl) {
        float acc = 0.f;
        #pragma unroll
        for (int u = 0; u < 6; ++u) {
            unsigned long long mm = mbase[nl * 6 + u];
            while (mm) {
                int j = __builtin_ctzll(mm);
                mm &= mm - 1;
                int row = 128 * (u >> 1) + 2 * j + (u & 1);
                acc += wpT[(size_t)row * 384 + tid];
            }
        }
        out[(obase + tid) * 1024 + g * 64 + nl] = (acc + bb) * pi + po;
    }
}

extern "C" void kernel_launch(void* const* d_in, const int* in_sizes, int n_in,
                              void* d_out, int out_size, void* d_ws, size_t ws_size,
                              hipStream_t stream) {
    const float* x  = (const float*)d_in[0];
    const unsigned char* ak = (const unsigned char*)d_in[1];
    const unsigned char* av = (const unsigned char*)d_in[2];
    const float* wq = (const float*)d_in[3];
    const float* qg = (const float*)d_in[4];
    const float* qb = (const float*)d_in[5];
    const float* qm = (const float*)d_in[6];
    const float* qv = (const float*)d_in[7];
    const float* wp = (const float*)d_in[8];
    const float* bp = (const float*)d_in[9];
    const float* pg = (const float*)d_in[10];
    const float* pb = (const float*)d_in[11];
    const float* pm = (const float*)d_in[12];
    const float* pv = (const float*)d_in[13];
    char* ws = (char*)d_ws;
    float* out = (float*)d_out;

    hipLaunchKernelGGL(k0_transpose, dim3(1154), dim3(256), 0, stream, wq, wp, ws);
    hipLaunchKernelGGL(k0_consts, dim3(1), dim3(384), 0, stream,
                       qg, qb, qm, qv, pg, pb, pm, pv, bp, ws);
    hipLaunchKernelGGL(k1_lif, dim3(24576), dim3(256), 0, stream,
                       x, (unsigned long long*)(ws + XM_OFF));
    hipLaunchKernelGGL(k1b_transpose, dim3(1536), dim3(256), 0, stream,
                       (const unsigned long long*)(ws + XM_OFF),
                       (unsigned long long*)(ws + XMT_OFF));
    hipLaunchKernelGGL(k1c_lists, dim3(256), dim3(256), 0, stream,
                       (const unsigned long long*)(ws + XMT_OFF),
                       (unsigned short*)(ws + LISTS_OFF),
                       (unsigned char*)(ws + LCNT_OFF));
    hipLaunchKernelGGL(k2_qpath, dim3(1024), dim3(384), 0, stream,
                       (const char*)(ws + WQB_OFF),
                       (const float*)(ws + QINV_OFF), (const float*)(ws + QOFF_OFF),
                       (const unsigned short*)(ws + LISTS_OFF),
                       (const unsigned char*)(ws + LCNT_OFF),
                       (const unsigned long long*)(ws + XMT_OFF), ak, av,
                       (unsigned long long*)(ws + MST_OFF));
    hipLaunchKernelGGL(k3_proj, dim3(1024), dim3(384), 0, stream,
                       (const float*)(ws + WPT_OFF), (const float*)(ws + PINV_OFF),
                       (const float*)(ws + POFF_OFF), bp, (const float*)(ws + C0_OFF),
                       (const unsigned long long*)(ws + MST_OFF), out);
}

// Round 8
// 123.420 us; speedup vs baseline: 1.2072x; 1.2072x over previous
//
#include <hip/hip_runtime.h>
#include <cstdint>

#define CN (384*1024)          // 393216
#define BCN (16*CN)            // 6291456
#define EPS 1e-5f

// workspace layout (bytes)
#define WPT_OFF   0u           // f32[384][384] = 589824
#define WQB_OFF   589824u      // bf16-as-u16[385][384] (row 384 = zeros), ends 885504
#define QINV_OFF  1179648u
#define QOFF_OFF  (QINV_OFF + 1536u)
#define PINV_OFF  (QINV_OFF + 3072u)
#define POFF_OFF  (QINV_OFF + 4608u)
#define C0_OFF    (QINV_OFF + 6144u)
#define LCNT2_OFF 1187840u     // u8[1024 blocks][64 units], ends 1253376
#define XM_OFF    1310720u     // u64[4][16][16][384] n-packed spikes, ends 4456448
#define XMT_OFF   4456448u     // u64[4][16][1024][6] c-packed spikes, ends 7602176
#define LISTS2_OFF 7602176u    // u16[1024][64][24] offsets (idx*3), 3MB+slack, ends ~10748032
#define MST_OFF   XM_OFF       // masked q-spikes; reuses xm (dead after k1b)

// ---------------- K0a: transposes: wp -> f32 wpT, wq -> bf16 wqb (+ zero row) ------
__global__ __launch_bounds__(256) void k0_transpose(const float* __restrict__ wq,
                                                    const float* __restrict__ wp,
                                                    char* __restrict__ ws) {
    int bid = blockIdx.x;
    if (bid < 576) {
        int i = bid * 256 + threadIdx.x;             // 0..147455
        int c = i / 384, o = i % 384;
        ((float*)(ws + WPT_OFF))[c * 384 + o] = wp[o * 384 + c];
    } else {
        int j = (bid - 576) * 256 + threadIdx.x;     // 0..147967
        if (j >= 147840) return;                     // 385*384
        int r = j / 384, o = j % 384;
        unsigned short v = 0;
        if (r < 384) {
            unsigned u = __float_as_uint(wq[o * 384 + r]);
            v = (unsigned short)((u + 0x7fffu + ((u >> 16) & 1u)) >> 16);  // rne bf16
        }
        ((unsigned short*)(ws + WQB_OFF))[j] = v;
    }
}

// ---------------- K0b: BN constants ----------------
__global__ void k0_consts(const float* __restrict__ qg, const float* __restrict__ qb,
                          const float* __restrict__ qm, const float* __restrict__ qv,
                          const float* __restrict__ pg, const float* __restrict__ pb,
                          const float* __restrict__ pm, const float* __restrict__ pv,
                          const float* __restrict__ bp, char* __restrict__ ws) {
    int i = threadIdx.x;                         // 384 threads
    float qi = qg[i] / sqrtf(qv[i] + EPS);
    ((float*)(ws + QINV_OFF))[i] = qi;
    ((float*)(ws + QOFF_OFF))[i] = qb[i] - qm[i] * qi;
    float pi = pg[i] / sqrtf(pv[i] + EPS);
    float po = pb[i] - pm[i] * pi;
    ((float*)(ws + PINV_OFF))[i] = pi;
    ((float*)(ws + POFF_OFF))[i] = po;
    ((float*)(ws + C0_OFF))[i] = bp[i] * pi + po;   // output value when GEMM2 input is all-zero
}

// ---------------- K1: shortcut LIF -> n-packed spike bitmasks ----------------
__global__ __launch_bounds__(256) void k1_lif(const float* __restrict__ x,
                                              unsigned long long* __restrict__ xm) {
    int wid  = (blockIdx.x * 256 + threadIdx.x) >> 6;   // 0..98303
    int lane = threadIdx.x & 63;
    int c = wid % 384;
    int g = (wid / 384) & 15;
    int b = wid / (384 * 16);
    const float* xp = x + (size_t)b * CN + (size_t)c * 1024 + g * 64 + lane;
    float v = 0.f;
    #pragma unroll
    for (int t = 0; t < 4; ++t) {
        float xv = xp[(size_t)t * BCN];
        float h = v + (xv - v) * 0.5f;                  // v + (x - v)/tau, tau = 2
        bool s = (h >= 1.0f);
        unsigned long long m = __ballot(s);
        v = s ? 0.f : h;
        if (lane == 0) xm[(((size_t)t * 16 + b) * 16 + g) * 384 + c] = m;
    }
}

// ---------------- K1b: 64x64 bit transpose: n-packed -> c-packed ----------------
__global__ __launch_bounds__(256) void k1b_transpose(const unsigned long long* __restrict__ xm,
                                                     unsigned long long* __restrict__ xmT) {
    int wid  = (blockIdx.x * 256 + threadIdx.x) >> 6;   // 0..6143
    int lane = threadIdx.x & 63;
    int cg = wid % 6;
    int g  = (wid / 6) % 16;
    int tb = wid / 96;                                  // t*16 + b
    unsigned long long W = xm[((size_t)tb * 16 + g) * 384 + cg * 64 + lane];
    unsigned long long T = 0ull;
    #pragma unroll
    for (int k = 0; k < 64; ++k) {
        unsigned long long bk = __ballot((W >> k) & 1ull);  // bit c = spike(c, n=g*64+k)
        if (lane == k) T = bk;
    }
    xmT[((size_t)tb * 1024 + g * 64 + lane) * 6 + cg] = T;
}

// ---------------- K1c: c-packed bitmasks -> per-block u16 offset lists -------------
// Column (t,b,n) -> block (b*64 + n>>4), unit (n&15)*4 + t. Entry = row_idx*3
// (so <<8 gives the 768B-row byte offset). Pad to full 8-batches with 1152 (zero row).
// k>24: lcnt=0xFF -> k2 bitmask fallback (any-input correct).
__global__ __launch_bounds__(256) void k1c_lists(const unsigned long long* __restrict__ xmT,
                                                 unsigned short* __restrict__ lists2,
                                                 unsigned char* __restrict__ lcnt2) {
    int col = blockIdx.x * 256 + threadIdx.x;           // 0..65535 = ((t*16+b)<<10)+n
    int t = col >> 14, b = (col >> 10) & 15, n = col & 1023;
    int blockid = b * 64 + (n >> 4);
    int un = (n & 15) * 4 + t;
    const unsigned long long* mp = xmT + (size_t)col * 6;
    unsigned short* lp = lists2 + ((size_t)blockid * 64 + un) * 24;
    int k = 0;
    #pragma unroll
    for (int cg = 0; cg < 6; ++cg) {
        unsigned long long m = mp[cg];
        while (m) {
            int j = __builtin_ctzll(m);
            m &= m - 1;
            if (k < 24) lp[k] = (unsigned short)((cg * 64 + j) * 3);
            ++k;
        }
    }
    if (k > 24) { lcnt2[(size_t)blockid * 64 + un] = 0xFF; return; }
    int r = (k + 7) >> 3;
    for (int i = k; i < r * 8; ++i) lp[i] = 1152;       // 384*3 -> zero row
    lcnt2[(size_t)blockid * 64 + un] = (unsigned char)r;
}

// ---------------- K2: lane-cached-list gather GEMM1 + BN + q-LIF + attn mask -------
// block = (b, nt16); 384 threads = 2 n-streams x 192; thread owns o-pair (2pj, 2pj+1)
// read as one u32 (two bf16). Block's list metadata (3KB) is VGPR-lane-cached once;
// per unit, v_readlane pulls offsets into SGPRs -> uniform row pointers -> saddr loads.
#define BLO(w) __uint_as_float((w) << 16)
#define BHI(w) __uint_as_float((w) & 0xFFFF0000u)
#define G8(C0, C1, C2, C3) do {                                                   \
    const unsigned W0_ = (unsigned)__builtin_amdgcn_readlane((int)(C0), un);      \
    const unsigned W1_ = (unsigned)__builtin_amdgcn_readlane((int)(C1), un);      \
    const unsigned W2_ = (unsigned)__builtin_amdgcn_readlane((int)(C2), un);      \
    const unsigned W3_ = (unsigned)__builtin_amdgcn_readlane((int)(C3), un);      \
    const char* p0_ = wqc + ((size_t)(W0_ & 0xffffu) << 8);                       \
    const char* p1_ = wqc + ((size_t)(W0_ >> 16) << 8);                           \
    const char* p2_ = wqc + ((size_t)(W1_ & 0xffffu) << 8);                       \
    const char* p3_ = wqc + ((size_t)(W1_ >> 16) << 8);                           \
    const char* p4_ = wqc + ((size_t)(W2_ & 0xffffu) << 8);                       \
    const char* p5_ = wqc + ((size_t)(W2_ >> 16) << 8);                           \
    const char* p6_ = wqc + ((size_t)(W3_ & 0xffffu) << 8);                       \
    const char* p7_ = wqc + ((size_t)(W3_ >> 16) << 8);                           \
    const unsigned d0_ = *(const unsigned*)(p0_ + voff);                          \
    const unsigned d1_ = *(const unsigned*)(p1_ + voff);                          \
    const unsigned d2_ = *(const unsigned*)(p2_ + voff);                          \
    const unsigned d3_ = *(const unsigned*)(p3_ + voff);                          \
    const unsigned d4_ = *(const unsigned*)(p4_ + voff);                          \
    const unsigned d5_ = *(const unsigned*)(p5_ + voff);                          \
    const unsigned d6_ = *(const unsigned*)(p6_ + voff);                          \
    const unsigned d7_ = *(const unsigned*)(p7_ + voff);                          \
    AL += ((BLO(d0_) + BLO(d1_)) + (BLO(d2_) + BLO(d3_)))                         \
        + ((BLO(d4_) + BLO(d5_)) + (BLO(d6_) + BLO(d7_)));                        \
    AH += ((BHI(d0_) + BHI(d1_)) + (BHI(d2_) + BHI(d3_)))                         \
        + ((BHI(d4_) + BHI(d5_)) + (BHI(d6_) + BHI(d7_)));                        \
} while (0)

__global__ __launch_bounds__(384) void k2_qpath(const char* __restrict__ wqc,
                                                const float* __restrict__ qinv_,
                                                const float* __restrict__ qoff_,
                                                const unsigned short* __restrict__ lists2,
                                                const unsigned char* __restrict__ lcnt2,
                                                const unsigned long long* __restrict__ xmT,
                                                const unsigned char* __restrict__ ak,
                                                const unsigned char* __restrict__ av,
                                                unsigned long long* __restrict__ msT) {
    const int tid  = threadIdx.x;
    const int s    = tid / 192;                  // n-stream (waves 0-2 / 3-5)
    const int pj   = tid - s * 192;              // o-pair index 0..191
    const int lane = tid & 63;
    const int wv_  = (tid >> 6) % 3;             // wave within stream -> o-base 128*wv_
    const int nt   = blockIdx.x & 63;
    const int b    = blockIdx.x >> 6;
    const int voff = pj * 4;
    const float2 qi2 = ((const float2*)qinv_)[pj];
    const float2 qo2 = ((const float2*)qoff_)[pj];

    // lane-cache the block's gather metadata: lane u holds unit u's 24 u16 offsets
    const char* lb = (const char*)lists2 + (size_t)blockIdx.x * 3072 + lane * 48;
    const uint4 L0 = *(const uint4*)lb;           // slots 0-7
    const uint4 L1 = *(const uint4*)(lb + 16);    // slots 8-15
    const uint4 L2 = *(const uint4*)(lb + 32);    // slots 16-23
    const unsigned lcv = *(const unsigned*)((const char*)lcnt2
                          + (size_t)blockIdx.x * 64 + (lane & 15) * 4);

    for (int nlo = 0; nlo < 8; ++nlo) {
        const int n = nt * 16 + s * 8 + nlo;
        const unsigned lcw = (unsigned)__builtin_amdgcn_readlane((int)lcv, s * 8 + nlo);
        float aL[4], aH[4];
        #pragma unroll
        for (int t = 0; t < 4; ++t) {
            const int un = (s * 8 + nlo) * 4 + t;           // uniform per wave
            const unsigned r_ = (lcw >> (8 * t)) & 0xffu;
            float AL = 0.f, AH = 0.f;
            if (r_ == 0xffu) {                               // rare overflow fallback
                const int col = ((t * 16 + b) << 10) + n;
                const unsigned long long* mp = xmT + (size_t)col * 6;
                #pragma unroll
                for (int cg = 0; cg < 6; ++cg) {
                    unsigned long long mm = mp[cg];
                    while (mm) {
                        int j = __builtin_ctzll(mm);
                        mm &= mm - 1;
                        unsigned ww = *(const unsigned*)(wqc + (cg * 64 + j) * 768 + voff);
                        AL += BLO(ww); AH += BHI(ww);
                    }
                }
            } else if (r_) {
                G8(L0.x, L0.y, L0.z, L0.w);
                if (r_ >= 2) G8(L1.x, L1.y, L1.z, L1.w);
                if (r_ >= 3) G8(L2.x, L2.y, L2.z, L2.w);
            }
            aL[t] = AL; aH[t] = AH;
        }
        // BN + LIF + attn-mask epilogue for the two owned o's
        float vL = 0.f, vH = 0.f;
        #pragma unroll
        for (int t = 0; t < 4; ++t) {
            const int col = ((t * 16 + b) << 10) + n;
            float qL = aL[t] * qi2.x + qo2.x;
            float qH = aH[t] * qi2.y + qo2.y;
            float hL = 0.5f * (vL + qL);
            float hH = 0.5f * (vH + qH);
            bool sL = (hL >= 1.0f), sH = (hH >= 1.0f);
            vL = sL ? 0.f : hL;  vH = sH ? 0.f : hH;
            if (sL) {   // rare: attn-mask lookup only on q-spike
                size_t ix = ((size_t)((t * 16 + b) * 384 + 2 * pj) << 10) + n;
                sL = (ak[ix] != 0) && (av[ix] != 0);
            }
            if (sH) {
                size_t ix = ((size_t)((t * 16 + b) * 384 + 2 * pj + 1) << 10) + n;
                sH = (ak[ix] != 0) && (av[ix] != 0);
            }
            unsigned long long bL = __ballot(sL);
            unsigned long long bH = __ballot(sH);
            // word u=2*wv_+h: bit l -> o = 128*wv_ + 2*l + h
            if (lane == 0) {
                msT[(size_t)col * 6 + 2 * wv_]     = bL;
                msT[(size_t)col * 6 + 2 * wv_ + 1] = bH;
            }
        }
    }
}

// ---------------- K3: proj GEMM2 + bias + BN (gather-based, atomic-free) ----------
__global__ __launch_bounds__(384) void k3_proj(const float* __restrict__ wpT,
                                               const float* __restrict__ pinv_,
                                               const float* __restrict__ poff_,
                                               const float* __restrict__ bp,
                                               const float* __restrict__ c0,
                                               const unsigned long long* __restrict__ msT,
                                               float* __restrict__ out) {
    __shared__ unsigned int wflag[6];
    const int tid = threadIdx.x;
    const int bid = blockIdx.x;
    const int g = bid & 15, b = (bid >> 4) & 15, t = bid >> 8;
    const unsigned long long* mbase = msT + ((size_t)(t * 16 + b) * 1024 + g * 64) * 6;
    unsigned long long m = mbase[tid];           // 384 words: n-local = tid/6, u = tid%6
    unsigned long long anyb = __ballot(m != 0ull);
    if ((tid & 63) == 0) wflag[tid >> 6] = (anyb != 0ull) ? 1u : 0u;
    __syncthreads();
    unsigned int any = wflag[0] | wflag[1] | wflag[2] | wflag[3] | wflag[4] | wflag[5];
    size_t obase = (size_t)(t * 16 + b) * 384;

    if (!any) {
        // all-zero GEMM2 input: out = bp*inv + off, coalesced float4 stores
        #pragma unroll
        for (int k = 0; k < 16; ++k) {
            int i = tid + k * 384;               // 6144 float4 units in the (384o x 64n) tile
            int o = i >> 4, n4 = i & 15;
            float vv = c0[o];
            float4* dst = (float4*)out + (obase + o) * 256 + g * 16 + n4;
            *dst = make_float4(vv, vv, vv, vv);
        }
        return;
    }
    // slow path (never taken on this input): per-n VGPR gather.
    // word u: bit l -> input channel 128*(u>>1) + 2*l + (u&1)   [matches k2's layout]
    float pi = pinv_[tid], po = poff_[tid], bb = bp[tid];
    for (int nl = 0; nl < 64; ++nl) {
        float acc = 0.f;
        #pragma unroll
        for (int u = 0; u < 6; ++u) {
            unsigned long long mm = mbase[nl * 6 + u];
            while (mm) {
                int j = __builtin_ctzll(mm);
                mm &= mm - 1;
                int row = 128 * (u >> 1) + 2 * j + (u & 1);
                acc += wpT[(size_t)row * 384 + tid];
            }
        }
        out[(obase + tid) * 1024 + g * 64 + nl] = (acc + bb) * pi + po;
    }
}

extern "C" void kernel_launch(void* const* d_in, const int* in_sizes, int n_in,
                              void* d_out, int out_size, void* d_ws, size_t ws_size,
                              hipStream_t stream) {
    const float* x  = (const float*)d_in[0];
    const unsigned char* ak = (const unsigned char*)d_in[1];
    const unsigned char* av = (const unsigned char*)d_in[2];
    const float* wq = (const float*)d_in[3];
    const float* qg = (const float*)d_in[4];
    const float* qb = (const float*)d_in[5];
    const float* qm = (const float*)d_in[6];
    const float* qv = (const float*)d_in[7];
    const float* wp = (const float*)d_in[8];
    const float* bp = (const float*)d_in[9];
    const float* pg = (const float*)d_in[10];
    const float* pb = (const float*)d_in[11];
    const float* pm = (const float*)d_in[12];
    const float* pv = (const float*)d_in[13];
    char* ws = (char*)d_ws;
    float* out = (float*)d_out;

    hipLaunchKernelGGL(k0_transpose, dim3(1154), dim3(256), 0, stream, wq, wp, ws);
    hipLaunchKernelGGL(k0_consts, dim3(1), dim3(384), 0, stream,
                       qg, qb, qm, qv, pg, pb, pm, pv, bp, ws);
    hipLaunchKernelGGL(k1_lif, dim3(24576), dim3(256), 0, stream,
                       x, (unsigned long long*)(ws + XM_OFF));
    hipLaunchKernelGGL(k1b_transpose, dim3(1536), dim3(256), 0, stream,
                       (const unsigned long long*)(ws + XM_OFF),
                       (unsigned long long*)(ws + XMT_OFF));
    hipLaunchKernelGGL(k1c_lists, dim3(256), dim3(256), 0, stream,
                       (const unsigned long long*)(ws + XMT_OFF),
                       (unsigned short*)(ws + LISTS2_OFF),
                       (unsigned char*)(ws + LCNT2_OFF));
    hipLaunchKernelGGL(k2_qpath, dim3(1024), dim3(384), 0, stream,
                       (const char*)(ws + WQB_OFF),
                       (const float*)(ws + QINV_OFF), (const float*)(ws + QOFF_OFF),
                       (const unsigned short*)(ws + LISTS2_OFF),
                       (const unsigned char*)(ws + LCNT2_OFF),
                       (const unsigned long long*)(ws + XMT_OFF), ak, av,
                       (unsigned long long*)(ws + MST_OFF));
    hipLaunchKernelGGL(k3_proj, dim3(1024), dim3(384), 0, stream,
                       (const float*)(ws + WPT_OFF), (const float*)(ws + PINV_OFF),
                       (const float*)(ws + POFF_OFF), bp, (const float*)(ws + C0_OFF),
                       (const unsigned long long*)(ws + MST_OFF), out);
}

// Round 9
// 122.319 us; speedup vs baseline: 1.2181x; 1.0090x over previous
//
#include <hip/hip_runtime.h>
#include <cstdint>

#define CN (384*1024)          // 393216
#define BCN (16*CN)            // 6291456
#define EPS 1e-5f

typedef float f32x2 __attribute__((ext_vector_type(2)));

// workspace layout (bytes)
#define WPT_OFF   0u           // f32[384][384] = 589824
#define WQB_OFF   589824u      // bf16-as-u16[385][384] (row 384 = zeros), ends 885504
#define QINV_OFF  1179648u
#define QOFF_OFF  (QINV_OFF + 1536u)
#define PINV_OFF  (QINV_OFF + 3072u)
#define POFF_OFF  (QINV_OFF + 4608u)
#define C0_OFF    (QINV_OFF + 6144u)
#define LCNT2_OFF 1187840u     // u8[1024 blocks][64 units], ends 1253376
#define XM_OFF    1310720u     // u64[4][16][16][384] n-packed spikes, ends 4456448
#define XMT_OFF   4456448u     // u64[4][16][1024][6] c-packed spikes, ends 7602176
#define LISTS2_OFF 7602176u    // u16[1024][64][24] offsets (idx*3), ends ~10748032
#define MST_OFF   XM_OFF       // masked q-spikes; reuses xm (dead after k1b)

// ---------------- K0a: transposes: wp -> f32 wpT, wq -> bf16 wqb (+ zero row) ------
__global__ __launch_bounds__(256) void k0_transpose(const float* __restrict__ wq,
                                                    const float* __restrict__ wp,
                                                    char* __restrict__ ws) {
    int bid = blockIdx.x;
    if (bid < 576) {
        int i = bid * 256 + threadIdx.x;             // 0..147455
        int c = i / 384, o = i % 384;
        ((float*)(ws + WPT_OFF))[c * 384 + o] = wp[o * 384 + c];
    } else {
        int j = (bid - 576) * 256 + threadIdx.x;     // 0..147967
        if (j >= 147840) return;                     // 385*384
        int r = j / 384, o = j % 384;
        unsigned short v = 0;
        if (r < 384) {
            unsigned u = __float_as_uint(wq[o * 384 + r]);
            v = (unsigned short)((u + 0x7fffu + ((u >> 16) & 1u)) >> 16);  // rne bf16
        }
        ((unsigned short*)(ws + WQB_OFF))[j] = v;
    }
}

// ---------------- K0b: BN constants ----------------
__global__ void k0_consts(const float* __restrict__ qg, const float* __restrict__ qb,
                          const float* __restrict__ qm, const float* __restrict__ qv,
                          const float* __restrict__ pg, const float* __restrict__ pb,
                          const float* __restrict__ pm, const float* __restrict__ pv,
                          const float* __restrict__ bp, char* __restrict__ ws) {
    int i = threadIdx.x;                         // 384 threads
    float qi = qg[i] / sqrtf(qv[i] + EPS);
    ((float*)(ws + QINV_OFF))[i] = qi;
    ((float*)(ws + QOFF_OFF))[i] = qb[i] - qm[i] * qi;
    float pi = pg[i] / sqrtf(pv[i] + EPS);
    float po = pb[i] - pm[i] * pi;
    ((float*)(ws + PINV_OFF))[i] = pi;
    ((float*)(ws + POFF_OFF))[i] = po;
    ((float*)(ws + C0_OFF))[i] = bp[i] * pi + po;   // output value when GEMM2 input is all-zero
}

// ---------------- K1: shortcut LIF -> n-packed spike bitmasks ----------------
__global__ __launch_bounds__(256) void k1_lif(const float* __restrict__ x,
                                              unsigned long long* __restrict__ xm) {
    int wid  = (blockIdx.x * 256 + threadIdx.x) >> 6;   // 0..98303
    int lane = threadIdx.x & 63;
    int c = wid % 384;
    int g = (wid / 384) & 15;
    int b = wid / (384 * 16);
    const float* xp = x + (size_t)b * CN + (size_t)c * 1024 + g * 64 + lane;
    float v = 0.f;
    #pragma unroll
    for (int t = 0; t < 4; ++t) {
        float xv = xp[(size_t)t * BCN];
        float h = v + (xv - v) * 0.5f;                  // v + (x - v)/tau, tau = 2
        bool s = (h >= 1.0f);
        unsigned long long m = __ballot(s);
        v = s ? 0.f : h;
        if (lane == 0) xm[(((size_t)t * 16 + b) * 16 + g) * 384 + c] = m;
    }
}

// ---------------- K1b: 64x64 bit transpose: n-packed -> c-packed ----------------
__global__ __launch_bounds__(256) void k1b_transpose(const unsigned long long* __restrict__ xm,
                                                     unsigned long long* __restrict__ xmT) {
    int wid  = (blockIdx.x * 256 + threadIdx.x) >> 6;   // 0..6143
    int lane = threadIdx.x & 63;
    int cg = wid % 6;
    int g  = (wid / 6) % 16;
    int tb = wid / 96;                                  // t*16 + b
    unsigned long long W = xm[((size_t)tb * 16 + g) * 384 + cg * 64 + lane];
    unsigned long long T = 0ull;
    #pragma unroll
    for (int k = 0; k < 64; ++k) {
        unsigned long long bk = __ballot((W >> k) & 1ull);  // bit c = spike(c, n=g*64+k)
        if (lane == k) T = bk;
    }
    xmT[((size_t)tb * 1024 + g * 64 + lane) * 6 + cg] = T;
}

// ---------------- K1c: c-packed bitmasks -> per-block u16 offset lists -------------
// Column (t,b,n) -> block (b*64 + n>>4), unit (n&15)*4 + t. Entry = row_idx*3
// (<<8 gives the 768B-row byte offset). ALL 24 slots always written (pad = 1152,
// the zero row) so k2's hot path is branchless. k>24: lcnt=0xFF -> bitmask fallback.
__global__ __launch_bounds__(256) void k1c_lists(const unsigned long long* __restrict__ xmT,
                                                 unsigned short* __restrict__ lists2,
                                                 unsigned char* __restrict__ lcnt2) {
    int col = blockIdx.x * 256 + threadIdx.x;           // 0..65535 = ((t*16+b)<<10)+n
    int t = col >> 14, b = (col >> 10) & 15, n = col & 1023;
    int blockid = b * 64 + (n >> 4);
    int un = (n & 15) * 4 + t;
    const unsigned long long* mp = xmT + (size_t)col * 6;
    unsigned short* lp = lists2 + ((size_t)blockid * 64 + un) * 24;
    int k = 0;
    #pragma unroll
    for (int cg = 0; cg < 6; ++cg) {
        unsigned long long m = mp[cg];
        while (m) {
            int j = __builtin_ctzll(m);
            m &= m - 1;
            if (k < 24) lp[k] = (unsigned short)((cg * 64 + j) * 3);
            ++k;
        }
    }
    int kk = k > 24 ? 24 : k;
    for (int i = kk; i < 24; ++i) lp[i] = 1152;         // 384*3 -> zero row (always pad)
    lcnt2[(size_t)blockid * 64 + un] =
        (k > 24) ? 0xFF : (unsigned char)((k + 7) >> 3);
}

// ---------------- K2: branchless lane-cached gather GEMM1 + BN + q-LIF + mask ------
// block = (b, nt16); 384 threads = 2 n-streams x 192; thread owns o-pair (2pj,2pj+1)
// read as one u32. Metadata VGPR-lane-cached; v_readlane -> SGPR row pointers ->
// saddr loads. Hot path = 2 unconditional G8s per (t) in ONE basic block (64 loads
// batched per nlo); third G8 / bitmask fallback are rare post-phases.
#define BLO(w) __uint_as_float((w) << 16)
#define BHI(w) __uint_as_float((w) & 0xFFFF0000u)
#define G8F(C0, C1, C2, C3) do {                                                  \
    const unsigned W0_ = (unsigned)__builtin_amdgcn_readlane((int)(C0), un);      \
    const unsigned W1_ = (unsigned)__builtin_amdgcn_readlane((int)(C1), un);      \
    const unsigned W2_ = (unsigned)__builtin_amdgcn_readlane((int)(C2), un);      \
    const unsigned W3_ = (unsigned)__builtin_amdgcn_readlane((int)(C3), un);      \
    const char* p0_ = wqc + ((size_t)(W0_ & 0xffffu) << 8);                       \
    const char* p1_ = wqc + ((size_t)(W0_ >> 16) << 8);                           \
    const char* p2_ = wqc + ((size_t)(W1_ & 0xffffu) << 8);                       \
    const char* p3_ = wqc + ((size_t)(W1_ >> 16) << 8);                           \
    const char* p4_ = wqc + ((size_t)(W2_ & 0xffffu) << 8);                       \
    const char* p5_ = wqc + ((size_t)(W2_ >> 16) << 8);                           \
    const char* p6_ = wqc + ((size_t)(W3_ & 0xffffu) << 8);                       \
    const char* p7_ = wqc + ((size_t)(W3_ >> 16) << 8);                           \
    const unsigned d0_ = *(const unsigned*)(p0_ + voff);                          \
    const unsigned d1_ = *(const unsigned*)(p1_ + voff);                          \
    const unsigned d2_ = *(const unsigned*)(p2_ + voff);                          \
    const unsigned d3_ = *(const unsigned*)(p3_ + voff);                          \
    const unsigned d4_ = *(const unsigned*)(p4_ + voff);                          \
    const unsigned d5_ = *(const unsigned*)(p5_ + voff);                          \
    const unsigned d6_ = *(const unsigned*)(p6_ + voff);                          \
    const unsigned d7_ = *(const unsigned*)(p7_ + voff);                          \
    f32x2 v0_ = {BLO(d0_), BHI(d0_)}, v1_ = {BLO(d1_), BHI(d1_)};                 \
    f32x2 v2_ = {BLO(d2_), BHI(d2_)}, v3_ = {BLO(d3_), BHI(d3_)};                 \
    f32x2 v4_ = {BLO(d4_), BHI(d4_)}, v5_ = {BLO(d5_), BHI(d5_)};                 \
    f32x2 v6_ = {BLO(d6_), BHI(d6_)}, v7_ = {BLO(d7_), BHI(d7_)};                 \
    A2 += ((v0_ + v1_) + (v2_ + v3_)) + ((v4_ + v5_) + (v6_ + v7_));              \
} while (0)

__global__ __launch_bounds__(384) void k2_qpath(const char* __restrict__ wqc,
                                                const float* __restrict__ qinv_,
                                                const float* __restrict__ qoff_,
                                                const unsigned short* __restrict__ lists2,
                                                const unsigned char* __restrict__ lcnt2,
                                                const unsigned long long* __restrict__ xmT,
                                                const unsigned char* __restrict__ ak,
                                                const unsigned char* __restrict__ av,
                                                unsigned long long* __restrict__ msT) {
    const int tid  = threadIdx.x;
    const int s    = tid / 192;                  // n-stream (waves 0-2 / 3-5)
    const int pj   = tid - s * 192;              // o-pair index 0..191
    const int lane = tid & 63;
    const int wv_  = (tid >> 6) % 3;             // wave within stream -> o-base 128*wv_
    const int nt   = blockIdx.x & 63;
    const int b    = blockIdx.x >> 6;
    const int voff = pj * 4;
    const float2 qi2 = ((const float2*)qinv_)[pj];
    const float2 qo2 = ((const float2*)qoff_)[pj];

    // lane-cache the block's gather metadata: lane u holds unit u's 24 u16 offsets
    const char* lb = (const char*)lists2 + (size_t)blockIdx.x * 3072 + lane * 48;
    const uint4 L0 = *(const uint4*)lb;           // slots 0-7
    const uint4 L1 = *(const uint4*)(lb + 16);    // slots 8-15
    const uint4 L2 = *(const uint4*)(lb + 32);    // slots 16-23
    const unsigned lcv = *(const unsigned*)((const char*)lcnt2
                          + (size_t)blockIdx.x * 64 + (lane & 15) * 4);

    for (int nlo = 0; nlo < 8; ++nlo) {
        const int n = nt * 16 + s * 8 + nlo;
        const unsigned lcw = (unsigned)__builtin_amdgcn_readlane((int)lcv, s * 8 + nlo);
        f32x2 acc2[4];
        // ---- phase 1: branchless bulk — 64 independent saddr loads in one block ----
        #pragma unroll
        for (int t = 0; t < 4; ++t) {
            const int un = (s * 8 + nlo) * 4 + t;           // wave-uniform
            f32x2 A2 = {0.f, 0.f};
            G8F(L0.x, L0.y, L0.z, L0.w);
            G8F(L1.x, L1.y, L1.z, L1.w);
            acc2[t] = A2;
        }
        // ---- phase 2: rare third round (k = 17..24), scalar-uniform branch ----
        #pragma unroll
        for (int t = 0; t < 4; ++t) {
            if (((lcw >> (8 * t)) & 0xffu) == 3u) {
                const int un = (s * 8 + nlo) * 4 + t;
                f32x2 A2 = acc2[t];
                G8F(L2.x, L2.y, L2.z, L2.w);
                acc2[t] = A2;
            }
        }
        // ---- phase 3: overflow fallback (k > 24, ~never), recompute from zero ----
        #pragma unroll
        for (int t = 0; t < 4; ++t) {
            if (((lcw >> (8 * t)) & 0xffu) == 0xffu) {
                const int col = ((t * 16 + b) << 10) + n;
                const unsigned long long* mp = xmT + (size_t)col * 6;
                f32x2 A2 = {0.f, 0.f};
                #pragma unroll
                for (int cg = 0; cg < 6; ++cg) {
                    unsigned long long mm = mp[cg];
                    while (mm) {
                        int j = __builtin_ctzll(mm);
                        mm &= mm - 1;
                        unsigned ww = *(const unsigned*)(wqc + (cg * 64 + j) * 768 + voff);
                        A2 += (f32x2){BLO(ww), BHI(ww)};
                    }
                }
                acc2[t] = A2;
            }
        }
        // ---- BN + LIF + attn-mask epilogue for the two owned o's ----
        float vL = 0.f, vH = 0.f;
        #pragma unroll
        for (int t = 0; t < 4; ++t) {
            const int col = ((t * 16 + b) << 10) + n;
            float qL = acc2[t].x * qi2.x + qo2.x;
            float qH = acc2[t].y * qi2.y + qo2.y;
            float hL = 0.5f * (vL + qL);
            float hH = 0.5f * (vH + qH);
            bool sL = (hL >= 1.0f), sH = (hH >= 1.0f);
            vL = sL ? 0.f : hL;  vH = sH ? 0.f : hH;
            if (sL) {   // rare: attn-mask lookup only on q-spike
                size_t ix = ((size_t)((t * 16 + b) * 384 + 2 * pj) << 10) + n;
                sL = (ak[ix] != 0) && (av[ix] != 0);
            }
            if (sH) {
                size_t ix = ((size_t)((t * 16 + b) * 384 + 2 * pj + 1) << 10) + n;
                sH = (ak[ix] != 0) && (av[ix] != 0);
            }
            unsigned long long bL = __ballot(sL);
            unsigned long long bH = __ballot(sH);
            // word u=2*wv_+h: bit l -> o = 128*wv_ + 2*l + h
            if (lane == 0) {
                msT[(size_t)col * 6 + 2 * wv_]     = bL;
                msT[(size_t)col * 6 + 2 * wv_ + 1] = bH;
            }
        }
    }
}

// ---------------- K3: proj GEMM2 + bias + BN (gather-based, atomic-free) ----------
__global__ __launch_bounds__(384) void k3_proj(const float* __restrict__ wpT,
                                               const float* __restrict__ pinv_,
                                               const float* __restrict__ poff_,
                                               const float* __restrict__ bp,
                                               const float* __restrict__ c0,
                                               const unsigned long long* __restrict__ msT,
                                               float* __restrict__ out) {
    __shared__ unsigned int wflag[6];
    const int tid = threadIdx.x;
    const int bid = blockIdx.x;
    const int g = bid & 15, b = (bid >> 4) & 15, t = bid >> 8;
    const unsigned long long* mbase = msT + ((size_t)(t * 16 + b) * 1024 + g * 64) * 6;
    unsigned long long m = mbase[tid];           // 384 words: n-local = tid/6, u = tid%6
    unsigned long long anyb = __ballot(m != 0ull);
    if ((tid & 63) == 0) wflag[tid >> 6] = (anyb != 0ull) ? 1u : 0u;
    __syncthreads();
    unsigned int any = wflag[0] | wflag[1] | wflag[2] | wflag[3] | wflag[4] | wflag[5];
    size_t obase = (size_t)(t * 16 + b) * 384;

    if (!any) {
        // all-zero GEMM2 input: out = bp*inv + off, coalesced float4 stores
        #pragma unroll
        for (int k = 0; k < 16; ++k) {
            int i = tid + k * 384;               // 6144 float4 units in the (384o x 64n) tile
            int o = i >> 4, n4 = i & 15;
            float vv = c0[o];
            float4* dst = (float4*)out + (obase + o) * 256 + g * 16 + n4;
            *dst = make_float4(vv, vv, vv, vv);
        }
        return;
    }
    // slow path (never taken on this input): per-n VGPR gather.
    // word u: bit l -> input channel 128*(u>>1) + 2*l + (u&1)   [matches k2's layout]
    float pi = pinv_[tid], po = poff_[tid], bb = bp[tid];
    for (int nl = 0; nl < 64; ++nl) {
        float acc = 0.f;
        #pragma unroll
        for (int u = 0; u < 6; ++u) {
            unsigned long long mm = mbase[nl * 6 + u];
            while (mm) {
                int j = __builtin_ctzll(mm);
                mm &= mm - 1;
                int row = 128 * (u >> 1) + 2 * j + (u & 1);
                acc += wpT[(size_t)row * 384 + tid];
            }
        }
        out[(obase + tid) * 1024 + g * 64 + nl] = (acc + bb) * pi + po;
    }
}

extern "C" void kernel_launch(void* const* d_in, const int* in_sizes, int n_in,
                              void* d_out, int out_size, void* d_ws, size_t ws_size,
                              hipStream_t stream) {
    const float* x  = (const float*)d_in[0];
    const unsigned char* ak = (const unsigned char*)d_in[1];
    const unsigned char* av = (const unsigned char*)d_in[2];
    const float* wq = (const float*)d_in[3];
    const float* qg = (const float*)d_in[4];
    const float* qb = (const float*)d_in[5];
    const float* qm = (const float*)d_in[6];
    const float* qv = (const float*)d_in[7];
    const float* wp = (const float*)d_in[8];
    const float* bp = (const float*)d_in[9];
    const float* pg = (const float*)d_in[10];
    const float* pb = (const float*)d_in[11];
    const float* pm = (const float*)d_in[12];
    const float* pv = (const float*)d_in[13];
    char* ws = (char*)d_ws;
    float* out = (float*)d_out;

    hipLaunchKernelGGL(k0_transpose, dim3(1154), dim3(256), 0, stream, wq, wp, ws);
    hipLaunchKernelGGL(k0_consts, dim3(1), dim3(384), 0, stream,
                       qg, qb, qm, qv, pg, pb, pm, pv, bp, ws);
    hipLaunchKernelGGL(k1_lif, dim3(24576), dim3(256), 0, stream,
                       x, (unsigned long long*)(ws + XM_OFF));
    hipLaunchKernelGGL(k1b_transpose, dim3(1536), dim3(256), 0, stream,
                       (const unsigned long long*)(ws + XM_OFF),
                       (unsigned long long*)(ws + XMT_OFF));
    hipLaunchKernelGGL(k1c_lists, dim3(256), dim3(256), 0, stream,
                       (const unsigned long long*)(ws + XMT_OFF),
                       (unsigned short*)(ws + LISTS2_OFF),
                       (unsigned char*)(ws + LCNT2_OFF));
    hipLaunchKernelGGL(k2_qpath, dim3(1024), dim3(384), 0, stream,
                       (const char*)(ws + WQB_OFF),
                       (const float*)(ws + QINV_OFF), (const float*)(ws + QOFF_OFF),
                       (const unsigned short*)(ws + LISTS2_OFF),
                       (const unsigned char*)(ws + LCNT2_OFF),
                       (const unsigned long long*)(ws + XMT_OFF), ak, av,
                       (unsigned long long*)(ws + MST_OFF));
    hipLaunchKernelGGL(k3_proj, dim3(1024), dim3(384), 0, stream,
                       (const float*)(ws + WPT_OFF), (const float*)(ws + PINV_OFF),
                       (const float*)(ws + POFF_OFF), bp, (const float*)(ws + C0_OFF),
                       (const unsigned long long*)(ws + MST_OFF), out);
}